// Round 2
// baseline (239.176 us; speedup 1.0000x reference)
//
#include <hip/hip_runtime.h>

#define IMG    384
#define IMG4   96            // float4 per image row
#define IMG2   (IMG*IMG)
#define CROP   378
#define BORD   3
#define NB     64
#define NI     7
#define R      8             // rows per stripe
#define SPB    8             // stripes per block
#define NGRP   6             // NGRP*SPB*R = 384 >= 378
#define PSTRIDE 64           // floats per (b,ii,grp) partial record

__device__ __forceinline__ float wave_sum_f(float v) {
    v += __shfl_down(v, 32);
    v += __shfl_down(v, 16);
    v += __shfl_down(v, 8);
    v += __shfl_down(v, 4);
    v += __shfl_down(v, 2);
    v += __shfl_down(v, 1);
    return v;
}

// LDS layouts:
//  lq4  : planar q = hr*mask, [R][96] float4; slot = y*96 + part*32 + l holds f4 c=3l+part
//         -> compute reads are 16B-stride dense (conflict-free), writes dense.
//  lmbu : mask bytes [R][96] u32; dword c holds bytes (0/1) for pixels 4c..4c+3.
//  lp4  : p rows [R][98] float4; row floats: [0..7]=0 pad, [8+u]=p(u) for u=0..377, tail zeros.
__global__ __launch_bounds__(256, 4)
void corr_kernel(const float* __restrict__ sr, const float* __restrict__ hr,
                 const float* __restrict__ mk, float* __restrict__ part)
{
    __shared__ float4   lq4[R*96];
    __shared__ unsigned lmbu[R*96];
    __shared__ float4   lp4[R*98];

    const int tid = threadIdx.x;
    // XCD-clustered decode: blocks of one batch stay on one XCD (id%8), batches sequential per XCD.
    const int id  = blockIdx.x;
    const int c8  = id & 7;
    const int k0  = id >> 3;          // 0..335
    const int b   = c8 + 8 * (k0 / 42);
    const int t0  = k0 % 42;
    const int ii  = t0 % 7;
    const int grp = t0 / 7;

    const float*  sb  = sr + (size_t)b * IMG2;
    const float*  hb  = hr + (size_t)b * IMG2;
    const float*  mb  = mk + (size_t)b * IMG2;
    const float4* hb4 = (const float4*)hb;
    const float4* mb4 = (const float4*)mb;

    const int l = tid & 31;           // chunk within row (12 px each)
    const int y = tid >> 5;           // row within stripe (0..7)

    float aA[7] = {0,0,0,0,0,0,0};
    float aB[7] = {0,0,0,0,0,0,0};
    float aC[7] = {0,0,0,0,0,0,0};
    float aSp = 0.f, aTm = 0.f, aTq = 0.f, aTq2 = 0.f;
    float em = 0.f, eq = 0.f, eq2 = 0.f;
    const int ecol = (tid < 6) ? tid : (372 + tid);   // tid 0..5 -> cols 0..5 ; 6..11 -> 378..383

    for (int ss = 0; ss < SPB; ++ss) {
        const int r0 = (grp * SPB + ss) * R;               // crop-row base
        const int yv = (CROP - r0 < R) ? (CROP - r0) : R;  // valid rows this stripe

        if (ss) __syncthreads();

        // ---- stage q (planar) + mask bytes: image rows r0+ii+y ----
        #pragma unroll
        for (int rep = 0; rep < 3; ++rep) {
            const int idx = tid + rep * 256;               // 0..767 == R*96
            const int yy = idx / 96, s = idx % 96;
            const int pt = s >> 5, ll = s & 31;
            const int c  = 3 * ll + pt;
            int gr = r0 + ii + yy; if (gr > IMG - 1) gr = IMG - 1;
            const float4 h4 = hb4[(size_t)gr * IMG4 + c];
            const float4 m4 = mb4[(size_t)gr * IMG4 + c];
            lq4[idx] = make_float4(h4.x * m4.x, h4.y * m4.y, h4.z * m4.z, h4.w * m4.w);
            const unsigned mw = (m4.x != 0.f ? 1u : 0u)
                              | (m4.y != 0.f ? 0x100u : 0u)
                              | (m4.z != 0.f ? 0x10000u : 0u)
                              | (m4.w != 0.f ? 0x1000000u : 0u);
            lmbu[yy * 96 + c] = mw;
        }
        // ---- stage p rows (center crop, image rows r0+y+3), zero-padded ----
        #pragma unroll
        for (int rep = 0; rep < 4; ++rep) {
            const int idx = tid + rep * 256;
            if (idx < R * 98) {
                const int yy = idx / 98, kk = idx % 98;
                float4 v = make_float4(0.f, 0.f, 0.f, 0.f);
                if (kk >= 2 && kk < 97) {
                    const int u0 = 4 * kk - 8;                     // 0..376
                    int prow = r0 + yy + BORD; if (prow > IMG - 1) prow = IMG - 1;
                    const float* srow = sb + (size_t)prow * IMG + (u0 + 3);
                    const float* mrow = mb + (size_t)prow * IMG + (u0 + 3);
                    v.x = srow[0] * mrow[0];
                    v.y = srow[1] * mrow[1];
                    const float z2 = srow[2] * mrow[2];
                    const float z3 = srow[3] * mrow[3];
                    v.z = (u0 + 2 < CROP) ? z2 : 0.f;
                    v.w = (u0 + 3 < CROP) ? z3 : 0.f;
                }
                lp4[yy * 98 + kk] = v;
            }
        }
        __syncthreads();

        // ---- accumulate ----
        if (y < yv) {
            // p window: floats (y*392 + 12l) .. +19 ; pw[t] = p(u = 12l + t - 8)
            const float4 P0 = lp4[y * 98 + 3 * l + 0];
            const float4 P1 = lp4[y * 98 + 3 * l + 1];
            const float4 P2 = lp4[y * 98 + 3 * l + 2];
            const float4 P3 = lp4[y * 98 + 3 * l + 3];
            const float4 P4 = lp4[y * 98 + 3 * l + 4];
            float pw[20] = {P0.x,P0.y,P0.z,P0.w, P1.x,P1.y,P1.z,P1.w,
                            P2.x,P2.y,P2.z,P2.w, P3.x,P3.y,P3.z,P3.w,
                            P4.x,P4.y,P4.z,P4.w};
            float p2w[18];
            #pragma unroll
            for (int s2 = 0; s2 < 18; ++s2) p2w[s2] = pw[2 + s2] * pw[2 + s2];
            #pragma unroll
            for (int k2 = 0; k2 < 12; ++k2) aSp += pw[8 + k2];

            const float4 Q0 = lq4[y * 96 + l];
            const float4 Q1 = lq4[y * 96 + 32 + l];
            const float4 Q2r = lq4[y * 96 + 64 + l];
            const unsigned mw0 = lmbu[y * 96 + 3 * l + 0];
            const unsigned mw1 = lmbu[y * 96 + 3 * l + 1];
            const unsigned mw2 = lmbu[y * 96 + 3 * l + 2];
            const float qe[12] = {Q0.x,Q0.y,Q0.z,Q0.w, Q1.x,Q1.y,Q1.z,Q1.w,
                                  Q2r.x,Q2r.y,Q2r.z,Q2r.w};
            float me[12];
            me[0] = (float)( mw0        & 255u); me[1] = (float)((mw0 >>  8) & 255u);
            me[2] = (float)((mw0 >> 16) & 255u); me[3] = (float)((mw0 >> 24) & 255u);
            me[4] = (float)( mw1        & 255u); me[5] = (float)((mw1 >>  8) & 255u);
            me[6] = (float)((mw1 >> 16) & 255u); me[7] = (float)((mw1 >> 24) & 255u);
            me[8] = (float)( mw2        & 255u); me[9] = (float)((mw2 >>  8) & 255u);
            me[10]= (float)((mw2 >> 16) & 255u); me[11]= (float)((mw2 >> 24) & 255u);

            #pragma unroll
            for (int k2 = 0; k2 < 12; ++k2) {
                const float qv = qe[k2], mv = me[k2];
                aTm += mv;
                aTq += qv;
                aTq2 = fmaf(qv, qv, aTq2);
                #pragma unroll
                for (int j2 = 0; j2 < 7; ++j2) {
                    const float pv = pw[k2 - j2 + 8];      // p(u = xq + k2 - j2)
                    aA[j2] = fmaf(pv,              qv, aA[j2]);
                    aB[j2] = fmaf(p2w[k2 - j2 + 6], mv, aB[j2]);
                    aC[j2] = fmaf(pv,              mv, aC[j2]);
                }
            }
        }
        // ---- 12 edge-column sums (cols 0..5, 378..383) over window rows ----
        if (tid < 12) {
            const int c = ecol >> 2, e = ecol & 3;
            const int slot = (c % 3) * 32 + c / 3;
            #pragma unroll
            for (int yy = 0; yy < R; ++yy) {
                if (yy < yv) {
                    const float qv = ((const float*)&lq4[yy * 96 + slot])[e];
                    const float mv = (float)((lmbu[yy * 96 + c] >> (8 * e)) & 255u);
                    em += mv;
                    eq += qv;
                    eq2 = fmaf(qv, qv, eq2);
                }
            }
        }
    }
    __syncthreads();

    // ---- block reduction of 25 values ----
    float* wbuf = (float*)lp4;          // reuse; need 4*32 floats
    const int wv = tid >> 6, ln = tid & 63;
    float vals[25];
    #pragma unroll
    for (int j2 = 0; j2 < 7; ++j2) { vals[j2] = aA[j2]; vals[7+j2] = aB[j2]; vals[14+j2] = aC[j2]; }
    vals[21] = aSp; vals[22] = aTm; vals[23] = aTq; vals[24] = aTq2;
    #pragma unroll
    for (int i2 = 0; i2 < 25; ++i2) {
        const float v = wave_sum_f(vals[i2]);
        if (ln == 0) wbuf[wv * 32 + i2] = v;
    }
    __syncthreads();
    float* po = part + (((size_t)b * NI + ii) * NGRP + grp) * PSTRIDE;
    if (tid < 25) po[tid] = wbuf[tid] + wbuf[32 + tid] + wbuf[64 + tid] + wbuf[96 + tid];
    if (tid < 12) { po[25 + tid] = em; po[37 + tid] = eq; po[49 + tid] = eq2; }
}

__global__ __launch_bounds__(64)
void mse_kernel(const float* __restrict__ part, double* __restrict__ bmin)
{
    const int b = blockIdx.x;
    const int s = threadIdx.x;          // 0..63, shifts 0..48 active
    double mse = 1e300;
    if (s < 49) {
        const int i = s / 7, j = s % 7;
        double A = 0, Bc = 0, Cc = 0, Sp = 0, N = 0, Sq = 0, Q2 = 0;
        double colm[12] = {0}, colq[12] = {0}, colq2[12] = {0};
        for (int g = 0; g < NGRP; ++g) {
            const float* p = part + (((size_t)b * NI + i) * NGRP + g) * PSTRIDE;
            A  += p[j];      Bc += p[7 + j];  Cc += p[14 + j];
            Sp += p[21];     N  += p[22];     Sq += p[23];     Q2 += p[24];
            #pragma unroll
            for (int t = 0; t < 12; ++t) {
                colm[t]  += p[25 + t];
                colq[t]  += p[37 + t];
                colq2[t] += p[49 + t];
            }
        }
        // exclude columns outside x-window [j, j+377]: left x=0..j-1 (t=x), right x=378+j..383 (t=x-372)
        #pragma unroll
        for (int t = 0; t < 12; ++t) {
            const bool excl = (t < j) || (t >= j + 6);
            if (excl) { N -= colm[t]; Sq -= colq[t]; Q2 -= colq2[t]; }
        }
        const double bb = (Sq - Sp) / N;
        mse = (Q2 - 2.0 * A - 2.0 * bb * Sq + Bc + 2.0 * bb * Cc + bb * bb * N) / N;
    }
    for (int off = 32; off; off >>= 1) {
        const double o = __shfl_down(mse, off);
        mse = fmin(mse, o);
    }
    if (s == 0) bmin[b] = mse;
}

__global__ __launch_bounds__(64)
void mean_kernel(const double* __restrict__ bmin, float* __restrict__ out)
{
    double v = bmin[threadIdx.x];
    for (int off = 32; off; off >>= 1) v += __shfl_down(v, off);
    if (threadIdx.x == 0) out[0] = (float)(v / 64.0);
}

extern "C" void kernel_launch(void* const* d_in, const int* in_sizes, int n_in,
                              void* d_out, int out_size, void* d_ws, size_t ws_size,
                              hipStream_t stream) {
    const float* sr = (const float*)d_in[0];
    const float* hr = (const float*)d_in[1];
    const float* mk = (const float*)d_in[2];

    float* part = (float*)d_ws;
    const size_t part_bytes = (size_t)NB * NI * NGRP * PSTRIDE * sizeof(float); // 688128
    double* bmin = (double*)((char*)d_ws + part_bytes);

    corr_kernel<<<dim3(NB * NI * NGRP), 256, 0, stream>>>(sr, hr, mk, part);
    mse_kernel<<<dim3(NB), 64, 0, stream>>>(part, bmin);
    mean_kernel<<<dim3(1), 64, 0, stream>>>(bmin, (float*)d_out);
}

// Round 3
// 121.157 us; speedup vs baseline: 1.9741x; 1.9741x over previous
//
#include <hip/hip_runtime.h>

#define IMG    384
#define IMG4   96            // float4 per image row
#define IMG2   (IMG*IMG)
#define CROP   378
#define NB     64
#define NI     7
#define R      8             // rows per stripe
#define SPB    8             // stripes per block
#define NGRP   6             // NGRP*SPB*R = 384 >= 378
#define PSTRIDE 64           // floats per (b,ii,grp) partial record

__device__ __forceinline__ float wave_sum_f(float v) {
    v += __shfl_down(v, 32);
    v += __shfl_down(v, 16);
    v += __shfl_down(v, 8);
    v += __shfl_down(v, 4);
    v += __shfl_down(v, 2);
    v += __shfl_down(v, 1);
    return v;
}

// Planar q layout: f4 column cf (0..95) lives at [part = cf%3][slot = cf/3].
// Compute reads per chunk l: slots {l, l+1} of each part-plane -> dense 16B
// stride ds_read_b128, conflict-free. Slot 32 is a zero pad (cols 384+).
__global__ __launch_bounds__(256)
void corr_kernel(const float* __restrict__ sr, const float* __restrict__ hr,
                 const float* __restrict__ mk, float* __restrict__ part)
{
    __shared__ float4   lq  [2][R][3][33];   // 25344 B, q = hr*mask
    __shared__ unsigned lmsk[2][R][3][33];   //  6336 B, mask bytes per f4-col
    __shared__ float    ebuf[3][96];         //  1152 B, edge partials

    const int tid = threadIdx.x;
    // XCD-clustered decode: all blocks of one batch stay on one XCD (id%8).
    const int id  = blockIdx.x;
    const int c8  = id & 7;
    const int k0  = id >> 3;          // 0..335
    const int b   = c8 + 8 * (k0 / 42);
    const int t0  = k0 % 42;
    const int ii  = t0 % 7;
    const int grp = t0 / 7;

    const float4* sb4 = (const float4*)(sr + (size_t)b * IMG2);
    const float4* hb4 = (const float4*)(hr + (size_t)b * IMG2);
    const float4* mb4 = (const float4*)(mk + (size_t)b * IMG2);

    const int l = tid & 31;           // chunk within row (12 px each)
    const int y = tid >> 5;           // row within stripe (0..7)

    // staging coordinates (fixed per thread, reused every stripe)
    int syy[3], sprt[3], sslt[3], sc[3];
    #pragma unroll
    for (int rep = 0; rep < 3; ++rep) {
        const int idx = tid + rep * 256;          // 0..767 = R*96 f4 columns
        const int yy = idx / 96, c = idx - yy * 96;
        const int sl = c / 3,   pt = c - sl * 3;
        syy[rep] = yy; sc[rep] = c; sprt[rep] = pt; sslt[rep] = sl;
    }

    // edge-thread coordinates (cols 0..5, 378..383) — valid when tid<96
    const int ec12 = tid >> 3, erow = tid & 7;
    const int ecol = (ec12 < 6) ? ec12 : (372 + ec12);
    const int ecf  = ecol >> 2;
    const int eprt = ecf % 3, eslt = ecf / 3, eel = ecol & 3;

    float aA[7] = {0,0,0,0,0,0,0};
    float aB[7] = {0,0,0,0,0,0,0};
    float aC[7] = {0,0,0,0,0,0,0};
    float aSp = 0.f, aTm = 0.f, aTq = 0.f, aTq2 = 0.f;
    float em = 0.f, eq = 0.f, eq2 = 0.f;

    float4 ph[3], pm[3];              // prefetch registers (issue-early)

    auto prefetch = [&](int ss) {
        const int r0 = (grp * SPB + ss) * R;
        #pragma unroll
        for (int rep = 0; rep < 3; ++rep) {
            int gr = r0 + ii + syy[rep]; if (gr > IMG - 1) gr = IMG - 1;
            const size_t o = (size_t)gr * IMG4 + sc[rep];
            ph[rep] = hb4[o];
            pm[rep] = mb4[o];
        }
    };
    auto stage = [&](int buf) {       // write-late
        #pragma unroll
        for (int rep = 0; rep < 3; ++rep) {
            const float4 h = ph[rep], m = pm[rep];
            float4 q; q.x = h.x*m.x; q.y = h.y*m.y; q.z = h.z*m.z; q.w = h.w*m.w;
            const unsigned mw = (m.x != 0.f ? 1u : 0u)
                              | (m.y != 0.f ? 0x100u : 0u)
                              | (m.z != 0.f ? 0x10000u : 0u)
                              | (m.w != 0.f ? 0x1000000u : 0u);
            lq  [buf][syy[rep]][sprt[rep]][sslt[rep]] = q;
            lmsk[buf][syy[rep]][sprt[rep]][sslt[rep]] = mw;
        }
    };

    // prologue: fill buffer 0, zero the slot-32 pads of both buffers
    prefetch(0);
    stage(0);
    if (tid < 48) {                   // 2 bufs * 8 rows * 3 parts
        const int bb = tid / 24, rem = tid - bb * 24;
        const int rr = rem / 3,  pp = rem - rr * 3;
        float4 z; z.x = z.y = z.z = z.w = 0.f;
        lq  [bb][rr][pp][32] = z;
        lmsk[bb][rr][pp][32] = 0u;
    }
    __syncthreads();

    for (int ss = 0; ss < SPB; ++ss) {
        const int cur = ss & 1;
        const int r0  = (grp * SPB + ss) * R;
        const int yv  = (CROP - r0 < R) ? (CROP - r0) : R;

        if (ss + 1 < SPB) prefetch(ss + 1);   // issue next-stripe loads early

        if (y < yv) {
            // ---- p: own 12 pixels from global (aligned f4, L1/L2-hot) ----
            const int pr = r0 + y + 3;               // center image row
            const size_t po_ = (size_t)pr * IMG4 + 3 * l;
            const float4 s0 = sb4[po_],   s1 = sb4[po_+1];
            const float4 s2 = sb4[po_+2], s3 = sb4[po_+3];
            const float4 w0 = mb4[po_],   w1 = mb4[po_+1];
            const float4 w2 = mb4[po_+2], w3 = mb4[po_+3];
            const float sf[16] = {s0.x,s0.y,s0.z,s0.w, s1.x,s1.y,s1.z,s1.w,
                                  s2.x,s2.y,s2.z,s2.w, s3.x,s3.y,s3.z,s3.w};
            const float wf[16] = {w0.x,w0.y,w0.z,w0.w, w1.x,w1.y,w1.z,w1.w,
                                  w2.x,w2.y,w2.z,w2.w, w3.x,w3.y,w3.z,w3.w};
            float pe[12];
            #pragma unroll
            for (int t = 0; t < 12; ++t) pe[t] = sf[3 + t] * wf[3 + t];
            if (l == 31) {                           // u=378..383 invalid
                pe[6] = pe[7] = pe[8] = pe[9] = pe[10] = pe[11] = 0.f;
            }

            // ---- q/m window: img cols 12l .. 12l+19 from planar LDS ----
            const float4 Q0 = lq[cur][y][0][l];
            const float4 Q1 = lq[cur][y][1][l];
            const float4 Q2v= lq[cur][y][2][l];
            const float4 Q3 = lq[cur][y][0][l + 1];
            const float4 Q4 = lq[cur][y][1][l + 1];
            const unsigned u0 = lmsk[cur][y][0][l];
            const unsigned u1 = lmsk[cur][y][1][l];
            const unsigned u2 = lmsk[cur][y][2][l];
            const unsigned u3 = lmsk[cur][y][0][l + 1];
            const unsigned u4 = lmsk[cur][y][1][l + 1];
            const float qf[20] = {Q0.x,Q0.y,Q0.z,Q0.w, Q1.x,Q1.y,Q1.z,Q1.w,
                                  Q2v.x,Q2v.y,Q2v.z,Q2v.w, Q3.x,Q3.y,Q3.z,Q3.w,
                                  Q4.x,Q4.y,Q4.z,Q4.w};
            float mf[20];
            mf[0] = (float)( u0        & 255u); mf[1] = (float)((u0 >>  8) & 255u);
            mf[2] = (float)((u0 >> 16) & 255u); mf[3] = (float)((u0 >> 24) & 255u);
            mf[4] = (float)( u1        & 255u); mf[5] = (float)((u1 >>  8) & 255u);
            mf[6] = (float)((u1 >> 16) & 255u); mf[7] = (float)((u1 >> 24) & 255u);
            mf[8] = (float)( u2        & 255u); mf[9] = (float)((u2 >>  8) & 255u);
            mf[10]= (float)((u2 >> 16) & 255u); mf[11]= (float)((u2 >> 24) & 255u);
            mf[12]= (float)( u3        & 255u); mf[13]= (float)((u3 >>  8) & 255u);
            mf[14]= (float)((u3 >> 16) & 255u); mf[15]= (float)((u3 >> 24) & 255u);
            mf[16]= (float)( u4        & 255u); mf[17]= (float)((u4 >>  8) & 255u);
            mf[18]= (float)((u4 >> 16) & 255u); mf[19]= (float)((u4 >> 24) & 255u);

            #pragma unroll
            for (int t = 0; t < 12; ++t) {
                const float p = pe[t], p2 = p * p;
                #pragma unroll
                for (int j = 0; j < 7; ++j) {
                    aA[j] = fmaf(p,  qf[t + j], aA[j]);
                    aB[j] = fmaf(p2, mf[t + j], aB[j]);
                    aC[j] = fmaf(p,  mf[t + j], aC[j]);
                }
                aSp += p;
                aTq += qf[t];
                aTq2 = fmaf(qf[t], qf[t], aTq2);
                aTm += mf[t];
            }
        }

        // ---- edge columns (0..5, 378..383), one px per thread ----
        if (tid < 96 && erow < yv) {
            const float qv = ((const float*)&lq[cur][erow][eprt][eslt])[eel];
            const float mv = (float)((lmsk[cur][erow][eprt][eslt] >> (8 * eel)) & 255u);
            em += mv;
            eq += qv;
            eq2 = fmaf(qv, qv, eq2);
        }

        if (ss + 1 < SPB) stage(cur ^ 1);   // write-late into other buffer
        __syncthreads();                     // single barrier per stripe
    }

    // ---- block reduction ----
    if (tid < 96) { ebuf[0][tid] = em; ebuf[1][tid] = eq; ebuf[2][tid] = eq2; }

    float vals[25];
    #pragma unroll
    for (int j = 0; j < 7; ++j) { vals[j] = aA[j]; vals[7+j] = aB[j]; vals[14+j] = aC[j]; }
    vals[21] = aSp; vals[22] = aTm; vals[23] = aTq; vals[24] = aTq2;

    float* wbuf = (float*)lq;               // safe: all LDS compute done
    const int wv = tid >> 6, ln = tid & 63;
    #pragma unroll
    for (int i2 = 0; i2 < 25; ++i2) {
        const float v = wave_sum_f(vals[i2]);
        if (ln == 0) wbuf[wv * 32 + i2] = v;
    }
    __syncthreads();

    float* po = part + (((size_t)b * NI + ii) * NGRP + grp) * PSTRIDE;
    if (tid < 25) po[tid] = wbuf[tid] + wbuf[32 + tid] + wbuf[64 + tid] + wbuf[96 + tid];
    if (tid < 12) {
        float sm = 0.f, sq = 0.f, sq2 = 0.f;
        #pragma unroll
        for (int rr = 0; rr < 8; ++rr) {
            sm  += ebuf[0][tid * 8 + rr];
            sq  += ebuf[1][tid * 8 + rr];
            sq2 += ebuf[2][tid * 8 + rr];
        }
        po[25 + tid] = sm; po[37 + tid] = sq; po[49 + tid] = sq2;
    }
}

__global__ __launch_bounds__(64)
void mse_kernel(const float* __restrict__ part, double* __restrict__ bmin)
{
    const int b = blockIdx.x;
    const int s = threadIdx.x;          // 0..63, shifts 0..48 active
    double mse = 1e300;
    if (s < 49) {
        const int i = s / 7, j = s % 7;
        double A = 0, Bc = 0, Cc = 0, Sp = 0, N = 0, Sq = 0, Q2 = 0;
        double colm[12] = {0}, colq[12] = {0}, colq2[12] = {0};
        for (int g = 0; g < NGRP; ++g) {
            const float* p = part + (((size_t)b * NI + i) * NGRP + g) * PSTRIDE;
            A  += p[j];      Bc += p[7 + j];  Cc += p[14 + j];
            Sp += p[21];     N  += p[22];     Sq += p[23];     Q2 += p[24];
            #pragma unroll
            for (int t = 0; t < 12; ++t) {
                colm[t]  += p[25 + t];
                colq[t]  += p[37 + t];
                colq2[t] += p[49 + t];
            }
        }
        // exclude cols outside x-window [j, j+377]: left x=0..j-1 (t=x),
        // right x=378+j..383 (t=x-372)
        #pragma unroll
        for (int t = 0; t < 12; ++t) {
            const bool excl = (t < j) || (t >= j + 6);
            if (excl) { N -= colm[t]; Sq -= colq[t]; Q2 -= colq2[t]; }
        }
        const double bb = (Sq - Sp) / N;
        mse = (Q2 - 2.0 * A - 2.0 * bb * Sq + Bc + 2.0 * bb * Cc + bb * bb * N) / N;
    }
    for (int off = 32; off; off >>= 1) {
        const double o = __shfl_down(mse, off);
        mse = fmin(mse, o);
    }
    if (s == 0) bmin[b] = mse;
}

__global__ __launch_bounds__(64)
void mean_kernel(const double* __restrict__ bmin, float* __restrict__ out)
{
    double v = bmin[threadIdx.x];
    for (int off = 32; off; off >>= 1) v += __shfl_down(v, off);
    if (threadIdx.x == 0) out[0] = (float)(v / 64.0);
}

extern "C" void kernel_launch(void* const* d_in, const int* in_sizes, int n_in,
                              void* d_out, int out_size, void* d_ws, size_t ws_size,
                              hipStream_t stream) {
    const float* sr = (const float*)d_in[0];
    const float* hr = (const float*)d_in[1];
    const float* mk = (const float*)d_in[2];

    float* part = (float*)d_ws;
    const size_t part_bytes = (size_t)NB * NI * NGRP * PSTRIDE * sizeof(float); // 688128
    double* bmin = (double*)((char*)d_ws + part_bytes);

    corr_kernel<<<dim3(NB * NI * NGRP), 256, 0, stream>>>(sr, hr, mk, part);
    mse_kernel<<<dim3(NB), 64, 0, stream>>>(part, bmin);
    mean_kernel<<<dim3(1), 64, 0, stream>>>(bmin, (float*)d_out);
}

// Round 4
// 112.916 us; speedup vs baseline: 2.1182x; 1.0730x over previous
//
#include <hip/hip_runtime.h>

#define IMG    384
#define IMG4   96
#define IMG2   (IMG*IMG)
#define CROP   378
#define NB     64
#define NGRP   12
#define NROWS  32      // crop rows per block
#define SPB    8       // stripes (4 rows each)
#define NTH    448     // 7 waves = 7 row-shifts
#define PSTR   424     // floats per (b,grp) record

__device__ __forceinline__ float wave_sum_f(float v) {
    v += __shfl_down(v, 32);
    v += __shfl_down(v, 16);
    v += __shfl_down(v, 8);
    v += __shfl_down(v, 4);
    v += __shfl_down(v, 2);
    v += __shfl_down(v, 1);
    return v;
}

// Planar LDS: f4 col c (0..95) -> [part=c%3][slot=c/3]; window reads are
// dense 16B-stride ds_read_b128 (conflict-free). 16-row circular buffer:
// stripe s reads local q-rows [4s,4s+9], stages [4s+10,4s+13] (disjoint mod 16).
__global__ __launch_bounds__(NTH, 4)
void corr_kernel(const float* __restrict__ sr, const float* __restrict__ hr,
                 const float* __restrict__ mk, float* __restrict__ part)
{
    __shared__ float4 lq[16][3][32];   // q = hr*mask
    __shared__ float4 lm[16][3][32];   // mask (f32)

    const int tid = threadIdx.x;
    // XCD-clustered: all 12 blocks of a batch on one XCD class
    const int id  = blockIdx.x;
    const int c8  = id & 7;
    const int k0  = id >> 3;
    const int b   = c8 + 8 * (k0 / NGRP);
    const int grp = k0 % NGRP;
    const int c0  = grp * NROWS;
    const int vrows = (CROP - c0 < NROWS) ? (CROP - c0) : NROWS;

    const float4* sb4 = (const float4*)(sr + (size_t)b * IMG2);
    const float4* hb4 = (const float4*)(hr + (size_t)b * IMG2);
    const float4* mb4 = (const float4*)(mk + (size_t)b * IMG2);

    const int w    = tid >> 6;        // wave index = row shift i
    const int lane = tid & 63;
    const int l    = lane & 31;       // 12-px chunk (cols 12l..12l+11)
    const int rsel = lane >> 5;       // row-within-pair
    const int l1   = (l + 1) & 31;

    // staging map (tid < 384): one f4 col of one new row
    const int ssub = tid / 96;
    const int sc   = tid % 96;
    const int spt  = sc % 3;
    const int ssl  = sc / 3;

    // edge map (tid < 84): (col-class t, shift i)
    const int et   = tid % 12;
    const int ei   = tid / 12;
    const int ecol = (et < 6) ? et : (372 + et);
    const int ecf  = ecol >> 2;
    const int ept  = ecf % 3;
    const int esl  = ecf / 3;
    const int esub = ecol & 3;

    float aA[7] = {0,0,0,0,0,0,0};
    float aB[7] = {0,0,0,0,0,0,0};
    float aC[7] = {0,0,0,0,0,0,0};
    float aTm = 0.f, aTq = 0.f, aTq2 = 0.f, aSp = 0.f;
    float eM = 0.f, eQ = 0.f, eQ2 = 0.f;

    // ---- prologue: stage local q-rows 0..9 ----
    for (int idx = tid; idx < 960; idx += NTH) {
        const int lr = idx / 96, c = idx % 96;
        const int pt = c % 3, sl = c / 3;
        int ir = c0 + lr; if (ir > IMG - 1) ir = IMG - 1;
        const float4 h = hb4[(size_t)ir * IMG4 + c];
        const float4 m = mb4[(size_t)ir * IMG4 + c];
        lq[lr & 15][pt][sl] = make_float4(h.x*m.x, h.y*m.y, h.z*m.z, h.w*m.w);
        lm[lr & 15][pt][sl] = m;
    }
    __syncthreads();

    for (int s = 0; s < SPB; ++s) {
        // ---- issue-early prefetch of 4 new rows (for stripe s+1) ----
        float4 ph = make_float4(0,0,0,0), pm = make_float4(0,0,0,0);
        const bool doStage = (tid < 384) && (s < SPB - 1);
        const int  slr = 4*s + 10 + ssub;
        if (doStage) {
            int ir = c0 + slr; if (ir > IMG - 1) ir = IMG - 1;
            ph = hb4[(size_t)ir * IMG4 + sc];
            pm = mb4[(size_t)ir * IMG4 + sc];
        }

        // ---- compute: 2 steps x 2 rows, wave w correlates at shift i=w ----
        #pragma unroll
        for (int step = 0; step < 2; ++step) {
            const int lr = 4*s + 2*step + rsel;     // local crop row
            if (lr < vrows) {
                const int cr = c0 + lr;
                // p = sr*mask for own 12 px: s from global, m from LDS row lr+3
                const int ms = (lr + 3) & 15;
                const float4 M0 = lm[ms][0][l];
                const float4 M1 = lm[ms][1][l];
                const float4 M2 = lm[ms][2][l];
                const float4 M3 = lm[ms][0][l1];
                const size_t so = (size_t)(cr + 3) * IMG4 + 3*l;
                const float4 S0 = sb4[so],   S1 = sb4[so+1];
                const float4 S2 = sb4[so+2], S3 = sb4[so+3];
                const float sf[16] = {S0.x,S0.y,S0.z,S0.w, S1.x,S1.y,S1.z,S1.w,
                                      S2.x,S2.y,S2.z,S2.w, S3.x,S3.y,S3.z,S3.w};
                const float mc[16] = {M0.x,M0.y,M0.z,M0.w, M1.x,M1.y,M1.z,M1.w,
                                      M2.x,M2.y,M2.z,M2.w, M3.x,M3.y,M3.z,M3.w};
                float pe[12], p2[12];
                #pragma unroll
                for (int t = 0; t < 12; ++t) pe[t] = sf[t+3] * mc[t+3];
                if (l == 31) {   // crop x >= 378 invalid
                    pe[6]=0.f; pe[7]=0.f; pe[8]=0.f; pe[9]=0.f; pe[10]=0.f; pe[11]=0.f;
                }
                #pragma unroll
                for (int t = 0; t < 12; ++t) p2[t] = pe[t] * pe[t];
                if (w == 0) {
                    #pragma unroll
                    for (int t = 0; t < 12; ++t) aSp += pe[t];
                }

                // q/m window at q-row lr+w, cols 12l..12l+17 (+2 slack)
                const int qs = (lr + w) & 15;
                const float4 Q0 = lq[qs][0][l];
                const float4 Q1 = lq[qs][1][l];
                const float4 Q2 = lq[qs][2][l];
                const float4 Q3 = lq[qs][0][l1];
                const float4 Q4 = lq[qs][1][l1];
                const float4 N0 = lm[qs][0][l];
                const float4 N1 = lm[qs][1][l];
                const float4 N2 = lm[qs][2][l];
                const float4 N3 = lm[qs][0][l1];
                const float4 N4 = lm[qs][1][l1];
                const float qf[20] = {Q0.x,Q0.y,Q0.z,Q0.w, Q1.x,Q1.y,Q1.z,Q1.w,
                                      Q2.x,Q2.y,Q2.z,Q2.w, Q3.x,Q3.y,Q3.z,Q3.w,
                                      Q4.x,Q4.y,Q4.z,Q4.w};
                const float mf[20] = {N0.x,N0.y,N0.z,N0.w, N1.x,N1.y,N1.z,N1.w,
                                      N2.x,N2.y,N2.z,N2.w, N3.x,N3.y,N3.z,N3.w,
                                      N4.x,N4.y,N4.z,N4.w};
                // NOTE: lane 31's qf/mf[12..19] are garbage (wrapped slot) but
                // are only multiplied by pe/p2[t>=6] which are zeroed there.

                #pragma unroll
                for (int t = 0; t < 12; ++t) {
                    aTm += mf[t];
                    aTq += qf[t];
                    aTq2 = fmaf(qf[t], qf[t], aTq2);
                    const float p = pe[t], pp = p2[t];
                    #pragma unroll
                    for (int j = 0; j < 7; ++j) {
                        aA[j] = fmaf(p,  qf[t+j], aA[j]);
                        aB[j] = fmaf(pp, mf[t+j], aB[j]);
                        aC[j] = fmaf(p,  mf[t+j], aC[j]);
                    }
                }
            }
        }

        // ---- 12 edge cols x 7 shifts on 84 dedicated lanes ----
        if (tid < 84) {
            #pragma unroll
            for (int y = 0; y < 4; ++y) {
                const int lr = 4*s + y;
                if (lr < vrows) {
                    const int qs2 = (lr + ei) & 15;
                    const float qv = ((const float*)&lq[qs2][ept][esl])[esub];
                    const float mv = ((const float*)&lm[qs2][ept][esl])[esub];
                    eM += mv;
                    eQ += qv;
                    eQ2 = fmaf(qv, qv, eQ2);
                }
            }
        }

        // ---- write-late stage into slots disjoint from this stripe's reads ----
        if (doStage) {
            lq[slr & 15][spt][ssl] = make_float4(ph.x*pm.x, ph.y*pm.y, ph.z*pm.z, ph.w*pm.w);
            lm[slr & 15][spt][ssl] = pm;
        }
        __syncthreads();     // single barrier per stripe
    }

    // ---- per-wave reduction, direct record writes ----
    float* po = part + ((size_t)b * NGRP + grp) * PSTR;
    float vals[24];
    #pragma unroll
    for (int j = 0; j < 7; ++j) { vals[j] = aA[j]; vals[7+j] = aB[j]; vals[14+j] = aC[j]; }
    vals[21] = aTm; vals[22] = aTq; vals[23] = aTq2;
    #pragma unroll
    for (int k = 0; k < 24; ++k) {
        const float v = wave_sum_f(vals[k]);
        if (lane == 0) {
            int off;
            if      (k <  7) off = w*7 + k;              // A[i][j]
            else if (k < 14) off = 49 + w*7 + (k-7);     // B
            else if (k < 21) off = 98 + w*7 + (k-14);    // C
            else if (k == 21) off = 147 + w;             // Tm(i)
            else if (k == 22) off = 154 + w;             // Tq(i)
            else              off = 161 + w;             // Tq2(i)
            po[off] = v;
        }
    }
    {
        const float sp = wave_sum_f(aSp);
        if (w == 0 && lane == 0) po[168] = sp;
    }
    if (tid < 84) {
        po[169 + ei*12 + et] = eM;
        po[253 + ei*12 + et] = eQ;
        po[337 + ei*12 + et] = eQ2;
    }
}

__global__ __launch_bounds__(64)
void mse_kernel(const float* __restrict__ part, double* __restrict__ bmin)
{
    const int b = blockIdx.x;
    const int s = threadIdx.x;           // shifts 0..48 active
    double mse = 1e300;
    if (s < 49) {
        const int i = s / 7, j = s % 7;
        double A=0, Bc=0, Cc=0, Tm=0, Tq=0, Tq2=0, Sp=0;
        for (int g = 0; g < NGRP; ++g) {
            const float* p = part + ((size_t)b * NGRP + g) * PSTR;
            A  += p[      i*7 + j];
            Bc += p[ 49 + i*7 + j];
            Cc += p[ 98 + i*7 + j];
            Tm += p[147 + i];
            Tq += p[154 + i];
            Tq2+= p[161 + i];
            Sp += p[168];
            #pragma unroll
            for (int t = 0; t < 12; ++t) {
                if (t < j || t >= j + 6) {   // col outside x-window [j, j+377]
                    Tm  -= p[169 + i*12 + t];
                    Tq  -= p[253 + i*12 + t];
                    Tq2 -= p[337 + i*12 + t];
                }
            }
        }
        const double bb = (Tq - Sp) / Tm;
        mse = (Tq2 - 2.0*A - 2.0*bb*Tq + Bc + 2.0*bb*Cc + bb*bb*Tm) / Tm;
    }
    for (int off = 32; off; off >>= 1) {
        const double o = __shfl_down(mse, off);
        mse = fmin(mse, o);
    }
    if (s == 0) bmin[b] = mse;
}

__global__ __launch_bounds__(64)
void mean_kernel(const double* __restrict__ bmin, float* __restrict__ out)
{
    double v = bmin[threadIdx.x];
    for (int off = 32; off; off >>= 1) v += __shfl_down(v, off);
    if (threadIdx.x == 0) out[0] = (float)(v / 64.0);
}

extern "C" void kernel_launch(void* const* d_in, const int* in_sizes, int n_in,
                              void* d_out, int out_size, void* d_ws, size_t ws_size,
                              hipStream_t stream) {
    const float* sr = (const float*)d_in[0];
    const float* hr = (const float*)d_in[1];
    const float* mk = (const float*)d_in[2];

    float* part = (float*)d_ws;
    const size_t part_bytes = (size_t)NB * NGRP * PSTR * sizeof(float);  // 1302528
    double* bmin = (double*)((char*)d_ws + part_bytes);

    corr_kernel<<<dim3(NB * NGRP), NTH, 0, stream>>>(sr, hr, mk, part);
    mse_kernel<<<dim3(NB), 64, 0, stream>>>(part, bmin);
    mean_kernel<<<dim3(1), 64, 0, stream>>>(bmin, (float*)d_out);
}